// Round 7
// baseline (144.230 us; speedup 1.0000x reference)
//
#include <hip/hip_runtime.h>
#include <math.h>

#define NCOLS 5000
#define NF4   1250            // NCOLS / 4
#define BLOCK 1024
#define NWAVES (BLOCK / 64)   // 16
#define NITER 2               // ceil(NF4 / BLOCK)
#define TOPKK 10
#define CAP 512               // candidate capacity (expected ~60-150/block)

// Monotone-ascending mapping float -> uint32 (total order on finite floats).
__device__ __forceinline__ unsigned mono_f32(float f) {
  unsigned u = __float_as_uint(f);
  return (u & 0x80000000u) ? ~u : (u | 0x80000000u);
}

__device__ __forceinline__ float wave_sum_f(float v) {
#pragma unroll
  for (int o = 1; o < 64; o <<= 1) v += __shfl_xor(v, o);
  return v;
}
__device__ __forceinline__ int wave_sum_i(int v) {
#pragma unroll
  for (int o = 1; o < 64; o <<= 1) v += __shfl_xor(v, o);
  return v;
}
__device__ __forceinline__ unsigned wave_max_u(unsigned v) {
#pragma unroll
  for (int o = 1; o < 64; o <<= 1) {
    unsigned w = __shfl_xor(v, o);
    v = w > v ? w : v;
  }
  return v;
}

extern "C" __global__ __launch_bounds__(BLOCK, 8)
void row_loss_kernel(const float* __restrict__ up, const float* __restrict__ down,
                     const float* __restrict__ yt, const int* __restrict__ masks,
                     float* __restrict__ out, float inv_nrows) {
  __shared__ float red_f[6][NWAVES];   // sq, sp, seyy, seyu, aspu, aspd
  __shared__ int red_i[NWAVES];        // nv partials
  __shared__ unsigned t1w_t[NWAVES];   // per-wave 10th-best key (top space)
  __shared__ unsigned t1w_b[NWAVES];   // per-wave 10th-best key (~key space)
  __shared__ unsigned keys_t[CAP];     // top candidate keys
  __shared__ int      col_t[CAP];      // their column index
  __shared__ unsigned keys_b[CAP];     // bottom candidate keys (~key)
  __shared__ int      col_b[CAP];
  __shared__ int ct, cb;
  __shared__ float s_res[2];           // SU, SD

  const int tid = threadIdx.x;
  const int lane = tid & 63;
  const int wv = tid >> 6;
  const int row = blockIdx.x;
  const long long b4 = (long long)row * NF4;
  const long long base = (long long)row * NCOLS;

  const float4* up4 = (const float4*)up + b4;
  const float4* dn4 = (const float4*)down + b4;
  const float4* yt4 = (const float4*)yt + b4;
  const int4*   mk4 = (const int4*)masks + b4;

  if (tid == 0) { ct = 0; cb = 0; }

  // ---- Single data pass, small register footprint (TLP hides latency:
  //      16 waves/block x 2 blocks/CU = full 32-wave CU capacity).
  unsigned km[NITER][4];               // valid ? mono(y) : 0
  int nv_l = 0;
  float sq = 0.f, sp = 0.f, seyy = 0.f, seyu = 0.f, aspu = 0.f, aspd = 0.f;
  // per-thread top-2 keys in each direction
  unsigned a0 = 0u, a1 = 0u, bb0 = 0u, bb1 = 0u;
#pragma unroll
  for (int j = 0; j < NITER; ++j) {
    const int f = j * BLOCK + tid;
    const int fc = f < NF4 ? f : NF4 - 1;  // clamp, keep loads unconditional
    const float4 y4 = yt4[fc];
    const float4 u4 = up4[fc];
    const float4 d4 = dn4[fc];
    const int4   m4 = mk4[fc];
    const bool inb = f < NF4;
    const float* yp = (const float*)&y4;
    const float* upp = (const float*)&u4;
    const float* dp = (const float*)&d4;
    const int* mp = (const int*)&m4;
#pragma unroll
    for (int c = 0; c < 4; ++c) {
      const bool valid = inb && (mp[c] > 0);
      const float y = yp[c], u = upp[c], d = dp[c];
      const unsigned kd = valid ? mono_f32(y) : 0u;
      const unsigned kb = valid ? ~kd : 0u;
      km[j][c] = kd;
      // top-2 insert (top space)
      if (kd > a1) { if (kd > a0) { a1 = a0; a0 = kd; } else a1 = kd; }
      // top-2 insert (~key space)
      if (kb > bb1) { if (kb > bb0) { bb1 = bb0; bb0 = kb; } else bb1 = kb; }
      if (valid) {
        nv_l++;
        const float ey = __expf(y);
        const float eu = __expf(u);
        const float ed = __expf(d);
        sq += ey;
        seyy += ey * y;
        seyu += ey * u;
        sp += eu;
        aspu += __logf(1.f + eu);   // softplus(u), |u|<~6 so no overflow
        aspd += __logf(1.f + ed);   // softplus(d)
      }
    }
  }

  // ---- Wave reduces of scalars.
  nv_l = wave_sum_i(nv_l);
  sq = wave_sum_f(sq);
  sp = wave_sum_f(sp);
  seyy = wave_sum_f(seyy);
  seyu = wave_sum_f(seyu);
  aspu = wave_sum_f(aspu);
  aspd = wave_sum_f(aspd);
  if (lane == 0) {
    red_i[wv] = nv_l;
    red_f[0][wv] = sq;  red_f[1][wv] = sp;
    red_f[2][wv] = seyy; red_f[3][wv] = seyu;
    red_f[4][wv] = aspu; red_f[5][wv] = aspd;
  }

  // ---- Per-wave filter: pop 10 rounds over top-2 lists. The 10 popped
  //      values are 10 distinct elements >= t1w, so >=10 elements >= t1
  //      block-wide => top-10 subset of {key >= t1}. Exactness preserved.
  {
    unsigned v0 = a0, v1 = a1, t1 = 0u;
#pragma unroll 1
    for (int r = 0; r < TOPKK; ++r) {
      unsigned m = wave_max_u(v0 > v1 ? v0 : v1);
      if (v0 == m) v0 = 0u;
      else if (v1 == m) v1 = 0u;
      t1 = m;
    }
    if (lane == 0) t1w_t[wv] = t1;
  }
  {
    unsigned v0 = bb0, v1 = bb1, t1 = 0u;
#pragma unroll 1
    for (int r = 0; r < TOPKK; ++r) {
      unsigned m = wave_max_u(v0 > v1 ? v0 : v1);
      if (v0 == m) v0 = 0u;
      else if (v1 == m) v1 = 0u;
      t1 = m;
    }
    if (lane == 0) t1w_b[wv] = t1;
  }
  __syncthreads();

  int nv = 0;
#pragma unroll
  for (int w = 0; w < NWAVES; ++w) nv += red_i[w];
  const int k = nv < TOPKK ? nv : TOPKK;

  unsigned t1 = 0u, t1b = 0u;
#pragma unroll
  for (int w = 0; w < NWAVES; ++w) {
    t1 = t1w_t[w] > t1 ? t1w_t[w] : t1;
    t1b = t1w_b[w] > t1b ? t1w_b[w] : t1b;
  }

  // ---- Compact candidate (key, column) pairs into LDS.
#pragma unroll
  for (int j = 0; j < NITER; ++j) {
#pragma unroll
    for (int c = 0; c < 4; ++c) {
      const unsigned kd = km[j][c];
      if (kd != 0u) {
        const int col = ((j * BLOCK + tid) << 2) + c;
        if (kd >= t1) {
          int i = atomicAdd(&ct, 1);
          if (i < CAP) { keys_t[i] = kd; col_t[i] = col; }
        }
        const unsigned kb = ~kd;
        if (kb >= t1b) {
          int i = atomicAdd(&cb, 1);
          if (i < CAP) { keys_b[i] = kb; col_b[i] = col; }
        }
      }
    }
  }
  __syncthreads();

  // ---- Wave 0: exact k-th top key + Sum u over top-k (L2-warm gather).
  if (wv == 0) {
    const int n = ct < CAP ? ct : CAP;
    unsigned kk[8];
#pragma unroll
    for (int i = 0; i < 8; ++i) {
      const int idx = i * 64 + lane;
      kk[i] = (idx < n) ? keys_t[idx] : 0u;
    }
    unsigned w0 = kk[0], w1 = kk[1], w2 = kk[2], w3 = kk[3];
    unsigned w4 = kk[4], w5 = kk[5], w6 = kk[6], w7 = kk[7];
    unsigned thr = 0xFFFFFFFFu;
#pragma unroll 1
    for (int r = 0; r < k; ++r) {
      unsigned l0 = w0 > w1 ? w0 : w1;
      unsigned l1 = w2 > w3 ? w2 : w3;
      unsigned l2 = w4 > w5 ? w4 : w5;
      unsigned l3 = w6 > w7 ? w6 : w7;
      l0 = l0 > l1 ? l0 : l1;
      l2 = l2 > l3 ? l2 : l3;
      unsigned m = wave_max_u(l0 > l2 ? l0 : l2);
      if (w0 == m) w0 = 0u;
      else if (w1 == m) w1 = 0u;
      else if (w2 == m) w2 = 0u;
      else if (w3 == m) w3 = 0u;
      else if (w4 == m) w4 = 0u;
      else if (w5 == m) w5 = 0u;
      else if (w6 == m) w6 = 0u;
      else if (w7 == m) w7 = 0u;
      thr = m;
    }
    float su = 0.f;
#pragma unroll
    for (int i = 0; i < 8; ++i) {
      const int idx = i * 64 + lane;
      if (kk[i] >= thr && kk[i] != 0u) su += up[base + col_t[idx]];
    }
    su = wave_sum_f(su);
    if (lane == 0) s_res[0] = su;
  } else if (wv == 1) {
    // ---- Wave 1: exact k-th bottom key + Sum d over bottom-k.
    const int n = cb < CAP ? cb : CAP;
    unsigned kk[8];
#pragma unroll
    for (int i = 0; i < 8; ++i) {
      const int idx = i * 64 + lane;
      kk[i] = (idx < n) ? keys_b[idx] : 0u;
    }
    unsigned w0 = kk[0], w1 = kk[1], w2 = kk[2], w3 = kk[3];
    unsigned w4 = kk[4], w5 = kk[5], w6 = kk[6], w7 = kk[7];
    unsigned thr = 0xFFFFFFFFu;
#pragma unroll 1
    for (int r = 0; r < k; ++r) {
      unsigned l0 = w0 > w1 ? w0 : w1;
      unsigned l1 = w2 > w3 ? w2 : w3;
      unsigned l2 = w4 > w5 ? w4 : w5;
      unsigned l3 = w6 > w7 ? w6 : w7;
      l0 = l0 > l1 ? l0 : l1;
      l2 = l2 > l3 ? l2 : l3;
      unsigned m = wave_max_u(l0 > l2 ? l0 : l2);
      if (w0 == m) w0 = 0u;
      else if (w1 == m) w1 = 0u;
      else if (w2 == m) w2 = 0u;
      else if (w3 == m) w3 = 0u;
      else if (w4 == m) w4 = 0u;
      else if (w5 == m) w5 = 0u;
      else if (w6 == m) w6 = 0u;
      else if (w7 == m) w7 = 0u;
      thr = m;
    }
    float sd = 0.f;
#pragma unroll
    for (int i = 0; i < 8; ++i) {
      const int idx = i * 64 + lane;
      if (kk[i] >= thr && kk[i] != 0u) sd += down[base + col_b[idx]];
    }
    sd = wave_sum_f(sd);
    if (lane == 0) s_res[1] = sd;
  }
  __syncthreads();

  if (tid == 0 && nv > 0) {
    float SQ = 0.f, SP = 0.f, SYY = 0.f, SYU = 0.f, ASU = 0.f, ASD = 0.f;
#pragma unroll
    for (int w = 0; w < NWAVES; ++w) {
      SQ += red_f[0][w]; SP += red_f[1][w];
      SYY += red_f[2][w]; SYU += red_f[3][w];
      ASU += red_f[4][w]; ASD += red_f[5][w];
    }
    const float SU = s_res[0];
    const float SD = s_res[1];
    // KL closed form: sum q*(logq - logp) = (Seyy - Seyu)/Sq - log(Sq) + log(Sp)
    const float kl = (SYY - SYU) / SQ - __logf(SQ) + __logf(SP);
    const float up_loss = ASU - SU;  // sum softplus(u) - sum_{topk} u
    const float dn_loss = ASD - SD;  // sum softplus(d) - sum_{botk} d
    const float loss = (up_loss + 0.5f * dn_loss + 0.3f * kl) / (float)nv;
    atomicAdd(out, loss * inv_nrows);
  }
}

extern "C" void kernel_launch(void* const* d_in, const int* in_sizes, int n_in,
                              void* d_out, int out_size, void* d_ws, size_t ws_size,
                              hipStream_t stream) {
  const float* up_logits   = (const float*)d_in[0];
  const float* down_logits = (const float*)d_in[1];
  const float* y_true      = (const float*)d_in[2];
  const int*   masks       = (const int*)d_in[3];

  const int nrows = in_sizes[0] / NCOLS;

  hipMemsetAsync(d_out, 0, sizeof(float) * (size_t)out_size, stream);
  row_loss_kernel<<<nrows, BLOCK, 0, stream>>>(up_logits, down_logits, y_true,
                                               masks, (float*)d_out,
                                               1.0f / (float)nrows);
}

// Round 8
// 135.294 us; speedup vs baseline: 1.0660x; 1.0660x over previous
//
#include <hip/hip_runtime.h>
#include <math.h>

#define NCOLS 5000
#define NF4   1250            // NCOLS / 4
#define BLOCK 640             // 10 waves: grid 1024 -> 4 blocks/CU -> up to 40 (cap 32) waves/CU
#define NWAVES (BLOCK / 64)   // 10
#define NITER 2               // 640*2 = 1280 f4-slots for 1250 (2% tail waste)
#define TOPKK 10
#define CAP 384               // candidate capacity (expected ~20-80/block)

// Monotone-ascending mapping float -> uint32 (total order on finite floats).
__device__ __forceinline__ unsigned mono_f32(float f) {
  unsigned u = __float_as_uint(f);
  return (u & 0x80000000u) ? ~u : (u | 0x80000000u);
}

__device__ __forceinline__ float wave_sum_f(float v) {
#pragma unroll
  for (int o = 1; o < 64; o <<= 1) v += __shfl_xor(v, o);
  return v;
}
__device__ __forceinline__ int wave_sum_i(int v) {
#pragma unroll
  for (int o = 1; o < 64; o <<= 1) v += __shfl_xor(v, o);
  return v;
}
__device__ __forceinline__ unsigned wave_max_u(unsigned v) {
#pragma unroll
  for (int o = 1; o < 64; o <<= 1) {
    unsigned w = __shfl_xor(v, o);
    v = w > v ? w : v;
  }
  return v;
}

extern "C" __global__ __launch_bounds__(BLOCK, 8)
void row_loss_kernel(const float* __restrict__ up, const float* __restrict__ down,
                     const float* __restrict__ yt, const int* __restrict__ masks,
                     float* __restrict__ out, float inv_nrows) {
  __shared__ float red_f[6][NWAVES];   // sq, sp, seyy, seyu, aspu, aspd
  __shared__ int red_i[NWAVES];        // nv partials
  __shared__ unsigned t1w_t[NWAVES];   // per-wave 10th-best key (top space)
  __shared__ unsigned t1w_b[NWAVES];   // per-wave 10th-best key (~key space)
  __shared__ unsigned keys_t[CAP];     // top candidate keys
  __shared__ int      col_t[CAP];
  __shared__ unsigned keys_b[CAP];     // bottom candidate keys (~key)
  __shared__ int      col_b[CAP];
  __shared__ int ct, cb;
  __shared__ float s_res[2];           // SU, SD

  const int tid = threadIdx.x;
  const int lane = tid & 63;
  const int wv = tid >> 6;
  const int row = blockIdx.x;
  const long long b4 = (long long)row * NF4;
  const long long base = (long long)row * NCOLS;

  const float4* up4 = (const float4*)up + b4;
  const float4* dn4 = (const float4*)down + b4;
  const float4* yt4 = (const float4*)yt + b4;
  const int4*   mk4 = (const int4*)masks + b4;

  if (tid == 0) { ct = 0; cb = 0; }

  // ---- Single data pass. Softplus sums use the product trick:
  //      sum log(1+e^x) = log prod(1+e^x); 8 factors/thread, each <= ~246
  //      => prod <= 1.3e19, safe in fp32. One __logf per thread per array.
  unsigned km[NITER][4];               // valid ? mono(y) : 0
  int nv_l = 0;
  float sq = 0.f, sp = 0.f, seyy = 0.f, seyu = 0.f;
  float pu = 1.f, pd = 1.f;            // running products for softplus sums
  unsigned a0 = 0u, a1 = 0u, bb0 = 0u, bb1 = 0u;  // per-thread top-2 keys
#pragma unroll
  for (int j = 0; j < NITER; ++j) {
    const int f = j * BLOCK + tid;
    const int fc = f < NF4 ? f : NF4 - 1;  // clamp, keep loads unconditional
    const float4 y4 = yt4[fc];
    const float4 u4 = up4[fc];
    const float4 d4 = dn4[fc];
    const int4   m4 = mk4[fc];
    const bool inb = f < NF4;
    const float* yp = (const float*)&y4;
    const float* upp = (const float*)&u4;
    const float* dp = (const float*)&d4;
    const int* mp = (const int*)&m4;
#pragma unroll
    for (int c = 0; c < 4; ++c) {
      const bool valid = inb && (mp[c] > 0);
      const float y = yp[c], u = upp[c], d = dp[c];
      const unsigned kd = valid ? mono_f32(y) : 0u;
      const unsigned kb = valid ? ~kd : 0u;
      km[j][c] = kd;
      if (kd > a1) { if (kd > a0) { a1 = a0; a0 = kd; } else a1 = kd; }
      if (kb > bb1) { if (kb > bb0) { bb1 = bb0; bb0 = kb; } else bb1 = kb; }
      const float ey = __expf(y);
      const float eu = __expf(u);
      const float ed = __expf(d);
      nv_l += valid ? 1 : 0;
      sq   += valid ? ey : 0.f;
      seyy += valid ? ey * y : 0.f;
      seyu += valid ? ey * u : 0.f;
      sp   += valid ? eu : 0.f;
      pu   *= valid ? (1.f + eu) : 1.f;
      pd   *= valid ? (1.f + ed) : 1.f;
    }
  }
  float aspu = __logf(pu);             // sum softplus(u) over this thread
  float aspd = __logf(pd);

  // ---- Wave reduces of scalars.
  nv_l = wave_sum_i(nv_l);
  sq = wave_sum_f(sq);
  sp = wave_sum_f(sp);
  seyy = wave_sum_f(seyy);
  seyu = wave_sum_f(seyu);
  aspu = wave_sum_f(aspu);
  aspd = wave_sum_f(aspd);
  if (lane == 0) {
    red_i[wv] = nv_l;
    red_f[0][wv] = sq;  red_f[1][wv] = sp;
    red_f[2][wv] = seyy; red_f[3][wv] = seyu;
    red_f[4][wv] = aspu; red_f[5][wv] = aspd;
  }

  // ---- Per-wave filter: pop 10 rounds over per-thread top-2 lists.
  //      The 10 popped values are distinct elements >= t1w, so block-wide
  //      >= 10 elements >= t1 => exact top-10 is a subset of {key >= t1}.
  {
    unsigned v0 = a0, v1 = a1, t1 = 0u;
#pragma unroll 1
    for (int r = 0; r < TOPKK; ++r) {
      unsigned m = wave_max_u(v0 > v1 ? v0 : v1);
      if (v0 == m) v0 = 0u;
      else if (v1 == m) v1 = 0u;
      t1 = m;
    }
    if (lane == 0) t1w_t[wv] = t1;
  }
  {
    unsigned v0 = bb0, v1 = bb1, t1 = 0u;
#pragma unroll 1
    for (int r = 0; r < TOPKK; ++r) {
      unsigned m = wave_max_u(v0 > v1 ? v0 : v1);
      if (v0 == m) v0 = 0u;
      else if (v1 == m) v1 = 0u;
      t1 = m;
    }
    if (lane == 0) t1w_b[wv] = t1;
  }
  __syncthreads();

  int nv = 0;
#pragma unroll
  for (int w = 0; w < NWAVES; ++w) nv += red_i[w];
  const int k = nv < TOPKK ? nv : TOPKK;

  unsigned t1 = 0u, t1b = 0u;
#pragma unroll
  for (int w = 0; w < NWAVES; ++w) {
    t1 = t1w_t[w] > t1 ? t1w_t[w] : t1;
    t1b = t1w_b[w] > t1b ? t1w_b[w] : t1b;
  }

  // ---- Compact candidate (key, column) pairs into LDS (~tens of atomics).
#pragma unroll
  for (int j = 0; j < NITER; ++j) {
#pragma unroll
    for (int c = 0; c < 4; ++c) {
      const unsigned kd = km[j][c];
      if (kd != 0u) {
        const int col = ((j * BLOCK + tid) << 2) + c;
        if (kd >= t1) {
          int i = atomicAdd(&ct, 1);
          if (i < CAP) { keys_t[i] = kd; col_t[i] = col; }
        }
        const unsigned kb = ~kd;
        if (kb >= t1b) {
          int i = atomicAdd(&cb, 1);
          if (i < CAP) { keys_b[i] = kb; col_b[i] = col; }
        }
      }
    }
  }
  __syncthreads();

  // ---- Wave 0: exact k-th top key + sum of u over top-k (L2-warm gather).
  if (wv == 0) {
    const int n = ct < CAP ? ct : CAP;
    unsigned kk[6];
#pragma unroll
    for (int i = 0; i < 6; ++i) {
      const int idx = i * 64 + lane;
      kk[i] = (idx < n) ? keys_t[idx] : 0u;
    }
    unsigned w0 = kk[0], w1 = kk[1], w2 = kk[2], w3 = kk[3], w4 = kk[4], w5 = kk[5];
    unsigned thr = 0xFFFFFFFFu;
#pragma unroll 1
    for (int r = 0; r < k; ++r) {
      unsigned l0 = w0 > w1 ? w0 : w1;
      unsigned l1 = w2 > w3 ? w2 : w3;
      unsigned l2 = w4 > w5 ? w4 : w5;
      l0 = l0 > l1 ? l0 : l1;
      unsigned m = wave_max_u(l0 > l2 ? l0 : l2);
      if (w0 == m) w0 = 0u;
      else if (w1 == m) w1 = 0u;
      else if (w2 == m) w2 = 0u;
      else if (w3 == m) w3 = 0u;
      else if (w4 == m) w4 = 0u;
      else if (w5 == m) w5 = 0u;
      thr = m;
    }
    float su = 0.f;
#pragma unroll
    for (int i = 0; i < 6; ++i) {
      const int idx = i * 64 + lane;
      if (kk[i] >= thr && kk[i] != 0u) su += up[base + col_t[idx]];
    }
    su = wave_sum_f(su);
    if (lane == 0) s_res[0] = su;
  } else if (wv == 1) {
    // ---- Wave 1: exact k-th bottom key + sum of d over bottom-k.
    const int n = cb < CAP ? cb : CAP;
    unsigned kk[6];
#pragma unroll
    for (int i = 0; i < 6; ++i) {
      const int idx = i * 64 + lane;
      kk[i] = (idx < n) ? keys_b[idx] : 0u;
    }
    unsigned w0 = kk[0], w1 = kk[1], w2 = kk[2], w3 = kk[3], w4 = kk[4], w5 = kk[5];
    unsigned thr = 0xFFFFFFFFu;
#pragma unroll 1
    for (int r = 0; r < k; ++r) {
      unsigned l0 = w0 > w1 ? w0 : w1;
      unsigned l1 = w2 > w3 ? w2 : w3;
      unsigned l2 = w4 > w5 ? w4 : w5;
      l0 = l0 > l1 ? l0 : l1;
      unsigned m = wave_max_u(l0 > l2 ? l0 : l2);
      if (w0 == m) w0 = 0u;
      else if (w1 == m) w1 = 0u;
      else if (w2 == m) w2 = 0u;
      else if (w3 == m) w3 = 0u;
      else if (w4 == m) w4 = 0u;
      else if (w5 == m) w5 = 0u;
      thr = m;
    }
    float sd = 0.f;
#pragma unroll
    for (int i = 0; i < 6; ++i) {
      const int idx = i * 64 + lane;
      if (kk[i] >= thr && kk[i] != 0u) sd += down[base + col_b[idx]];
    }
    sd = wave_sum_f(sd);
    if (lane == 0) s_res[1] = sd;
  }
  __syncthreads();

  if (tid == 0 && nv > 0) {
    float SQ = 0.f, SP = 0.f, SYY = 0.f, SYU = 0.f, ASU = 0.f, ASD = 0.f;
#pragma unroll
    for (int w = 0; w < NWAVES; ++w) {
      SQ += red_f[0][w]; SP += red_f[1][w];
      SYY += red_f[2][w]; SYU += red_f[3][w];
      ASU += red_f[4][w]; ASD += red_f[5][w];
    }
    const float SU = s_res[0];
    const float SD = s_res[1];
    // KL closed form: sum q*(logq - logp) = (Seyy - Seyu)/Sq - log(Sq) + log(Sp)
    const float kl = (SYY - SYU) / SQ - __logf(SQ) + __logf(SP);
    const float up_loss = ASU - SU;  // sum softplus(u) - sum_{topk} u
    const float dn_loss = ASD - SD;  // sum softplus(d) - sum_{botk} d
    const float loss = (up_loss + 0.5f * dn_loss + 0.3f * kl) / (float)nv;
    atomicAdd(out, loss * inv_nrows);
  }
}

extern "C" void kernel_launch(void* const* d_in, const int* in_sizes, int n_in,
                              void* d_out, int out_size, void* d_ws, size_t ws_size,
                              hipStream_t stream) {
  const float* up_logits   = (const float*)d_in[0];
  const float* down_logits = (const float*)d_in[1];
  const float* y_true      = (const float*)d_in[2];
  const int*   masks       = (const int*)d_in[3];

  const int nrows = in_sizes[0] / NCOLS;

  hipMemsetAsync(d_out, 0, sizeof(float) * (size_t)out_size, stream);
  row_loss_kernel<<<nrows, BLOCK, 0, stream>>>(up_logits, down_logits, y_true,
                                               masks, (float*)d_out,
                                               1.0f / (float)nrows);
}

// Round 9
// 125.043 us; speedup vs baseline: 1.1534x; 1.0820x over previous
//
#include <hip/hip_runtime.h>
#include <math.h>

#define NCOLS 5000
#define NF4   1250            // NCOLS / 4
#define BLOCK 256
#define NWAVES (BLOCK / 64)   // 4
#define NITER 5               // ceil(NF4 / BLOCK)
#define TOPKK 10
#define CAP 384               // candidate capacity (top-1 filter: expect ~50-150)

// Monotone-ascending mapping float -> uint32 (total order on finite floats).
__device__ __forceinline__ unsigned mono_f32(float f) {
  unsigned u = __float_as_uint(f);
  return (u & 0x80000000u) ? ~u : (u | 0x80000000u);
}

__device__ __forceinline__ float wave_sum_f(float v) {
#pragma unroll
  for (int o = 1; o < 64; o <<= 1) v += __shfl_xor(v, o);
  return v;
}
__device__ __forceinline__ int wave_sum_i(int v) {
#pragma unroll
  for (int o = 1; o < 64; o <<= 1) v += __shfl_xor(v, o);
  return v;
}
__device__ __forceinline__ unsigned wave_max_u(unsigned v) {
#pragma unroll
  for (int o = 1; o < 64; o <<= 1) {
    unsigned w = __shfl_xor(v, o);
    v = w > v ? w : v;
  }
  return v;
}

extern "C" __global__ __launch_bounds__(BLOCK, 4)
void row_loss_kernel(const float* __restrict__ up, const float* __restrict__ down,
                     const float* __restrict__ yt, const int* __restrict__ masks,
                     float* __restrict__ out, float inv_nrows) {
  __shared__ float red_f[6][NWAVES];   // sq, sp, seyy, seyu, aspu, aspd
  __shared__ int red_i[NWAVES];        // nv partials
  __shared__ unsigned t1w_t[NWAVES];   // per-wave 10th-best thread-max (top)
  __shared__ unsigned t1w_b[NWAVES];   // per-wave 10th-best thread-max (~key)
  __shared__ unsigned keys_t[CAP];     // top candidate keys
  __shared__ int      col_t[CAP];
  __shared__ unsigned keys_b[CAP];     // bottom candidate keys (~key space)
  __shared__ int      col_b[CAP];
  __shared__ int ct, cb;
  __shared__ float s_res[2];           // SU, SD

  const int tid = threadIdx.x;
  const int lane = tid & 63;
  const int wv = tid >> 6;
  const int row = blockIdx.x;
  const long long b4 = (long long)row * NF4;
  const long long base = (long long)row * NCOLS;

  const float4* up4 = (const float4*)up + b4;
  const float4* dn4 = (const float4*)down + b4;
  const float4* yt4 = (const float4*)yt + b4;
  const int4*   mk4 = (const int4*)masks + b4;

  if (tid == 0) { ct = 0; cb = 0; }

  // ---- Single data pass. Invalid elements get value fill -1000 so exp->0
  //      zeroes every sum contribution with NO per-term selects.
  unsigned km[NITER][4];               // valid ? mono(y) : 0
  int nv_l = 0;
  float sq = 0.f, sp = 0.f, seyy = 0.f, seyu = 0.f;
  float pu0 = 1.f, pu1 = 1.f, pd0 = 1.f, pd1 = 1.f;  // split softplus products
  unsigned tmax = 0u, tbmax = 0u;      // per-thread TOP-1 maxes (filter basis)
#pragma unroll
  for (int j = 0; j < NITER; ++j) {
    const int f = j * BLOCK + tid;
    const int fc = f < NF4 ? f : NF4 - 1;  // clamp; loads unconditional
    const float4 y4 = yt4[fc];
    const float4 u4 = up4[fc];
    const float4 d4 = dn4[fc];
    const int4   m4 = mk4[fc];
    const bool inb = f < NF4;
    const float* yp = (const float*)&y4;
    const float* upp = (const float*)&u4;
    const float* dp = (const float*)&d4;
    const int* mp = (const int*)&m4;
#pragma unroll
    for (int c = 0; c < 4; ++c) {
      const bool valid = inb && (mp[c] > 0);
      const float y = valid ? yp[c] : -1000.f;
      const float u = valid ? upp[c] : -1000.f;
      const float d = valid ? dp[c] : -1000.f;
      const unsigned kd = valid ? mono_f32(y) : 0u;
      const unsigned kb = valid ? ~kd : 0u;
      km[j][c] = kd;
      tmax = kd > tmax ? kd : tmax;
      tbmax = kb > tbmax ? kb : tbmax;
      nv_l += valid ? 1 : 0;
      const float ey = __expf(y);        // 0 for invalid
      const float eu = __expf(u);        // 0 for invalid
      const float ed = __expf(d);        // 0 for invalid
      sq += ey;
      seyy += ey * y;                    // 0 * -1000 = 0 (exp underflows to 0)
      seyu += ey * u;
      sp += eu;
      if (j < 3) { pu0 *= 1.f + eu; pd0 *= 1.f + ed; }
      else       { pu1 *= 1.f + eu; pd1 *= 1.f + ed; }
    }
  }
  float aspu = __logf(pu0) + __logf(pu1);  // sum softplus(u) this thread
  float aspd = __logf(pd0) + __logf(pd1);

  // ---- Wave reduces of scalars.
  nv_l = wave_sum_i(nv_l);
  sq = wave_sum_f(sq);
  sp = wave_sum_f(sp);
  seyy = wave_sum_f(seyy);
  seyu = wave_sum_f(seyu);
  aspu = wave_sum_f(aspu);
  aspd = wave_sum_f(aspd);
  if (lane == 0) {
    red_i[wv] = nv_l;
    red_f[0][wv] = sq;  red_f[1][wv] = sp;
    red_f[2][wv] = seyy; red_f[3][wv] = seyu;
    red_f[4][wv] = aspu; red_f[5][wv] = aspd;
  }

  // ---- Per-wave filter: 10 pop rounds over per-thread TOP-1 maxes.
  //      The 10 popped values are 10 distinct elements >= t1w => block-wide
  //      >=10 elements >= t1 => exact top-10 subset of {key >= t1}.
  {
    unsigned v = tmax, t1 = 0u;
#pragma unroll 1
    for (int r = 0; r < TOPKK; ++r) {
      unsigned m = wave_max_u(v);
      if (v == m) v = 0u;
      t1 = m;
    }
    if (lane == 0) t1w_t[wv] = t1;
  }
  {
    unsigned v = tbmax, t1 = 0u;
#pragma unroll 1
    for (int r = 0; r < TOPKK; ++r) {
      unsigned m = wave_max_u(v);
      if (v == m) v = 0u;
      t1 = m;
    }
    if (lane == 0) t1w_b[wv] = t1;
  }
  __syncthreads();

  int nv = 0;
#pragma unroll
  for (int w = 0; w < NWAVES; ++w) nv += red_i[w];
  const int k = nv < TOPKK ? nv : TOPKK;

  unsigned t1 = 0u, t1b = 0u;
#pragma unroll
  for (int w = 0; w < NWAVES; ++w) {
    t1 = t1w_t[w] > t1 ? t1w_t[w] : t1;
    t1b = t1w_b[w] > t1b ? t1w_b[w] : t1b;
  }

  // ---- Compact candidate (key, column) pairs into LDS.
#pragma unroll
  for (int j = 0; j < NITER; ++j) {
#pragma unroll
    for (int c = 0; c < 4; ++c) {
      const unsigned kd = km[j][c];
      if (kd != 0u) {
        const int col = ((j * BLOCK + tid) << 2) + c;
        if (kd >= t1) {
          int i = atomicAdd(&ct, 1);
          if (i < CAP) { keys_t[i] = kd; col_t[i] = col; }
        }
        const unsigned kb = ~kd;
        if (kb >= t1b) {
          int i = atomicAdd(&cb, 1);
          if (i < CAP) { keys_b[i] = kb; col_b[i] = col; }
        }
      }
    }
  }
  __syncthreads();

  // ---- Wave 0: exact k-th top key + sum of u over top-k (L2-warm gather).
  if (wv == 0) {
    const int n = ct < CAP ? ct : CAP;
    unsigned kk[6];
#pragma unroll
    for (int i = 0; i < 6; ++i) {
      const int idx = i * 64 + lane;
      kk[i] = (idx < n) ? keys_t[idx] : 0u;
    }
    unsigned w0 = kk[0], w1 = kk[1], w2 = kk[2], w3 = kk[3], w4 = kk[4], w5 = kk[5];
    unsigned thr = 0xFFFFFFFFu;
#pragma unroll 1
    for (int r = 0; r < k; ++r) {
      unsigned l0 = w0 > w1 ? w0 : w1;
      unsigned l1 = w2 > w3 ? w2 : w3;
      unsigned l2 = w4 > w5 ? w4 : w5;
      l0 = l0 > l1 ? l0 : l1;
      unsigned m = wave_max_u(l0 > l2 ? l0 : l2);
      if (w0 == m) w0 = 0u;
      else if (w1 == m) w1 = 0u;
      else if (w2 == m) w2 = 0u;
      else if (w3 == m) w3 = 0u;
      else if (w4 == m) w4 = 0u;
      else if (w5 == m) w5 = 0u;
      thr = m;
    }
    float su = 0.f;
#pragma unroll
    for (int i = 0; i < 6; ++i) {
      const int idx = i * 64 + lane;
      if (kk[i] >= thr && kk[i] != 0u) su += up[base + col_t[idx]];
    }
    su = wave_sum_f(su);
    if (lane == 0) s_res[0] = su;
  } else if (wv == 1) {
    // ---- Wave 1: exact k-th bottom key + sum of d over bottom-k.
    const int n = cb < CAP ? cb : CAP;
    unsigned kk[6];
#pragma unroll
    for (int i = 0; i < 6; ++i) {
      const int idx = i * 64 + lane;
      kk[i] = (idx < n) ? keys_b[idx] : 0u;
    }
    unsigned w0 = kk[0], w1 = kk[1], w2 = kk[2], w3 = kk[3], w4 = kk[4], w5 = kk[5];
    unsigned thr = 0xFFFFFFFFu;
#pragma unroll 1
    for (int r = 0; r < k; ++r) {
      unsigned l0 = w0 > w1 ? w0 : w1;
      unsigned l1 = w2 > w3 ? w2 : w3;
      unsigned l2 = w4 > w5 ? w4 : w5;
      l0 = l0 > l1 ? l0 : l1;
      unsigned m = wave_max_u(l0 > l2 ? l0 : l2);
      if (w0 == m) w0 = 0u;
      else if (w1 == m) w1 = 0u;
      else if (w2 == m) w2 = 0u;
      else if (w3 == m) w3 = 0u;
      else if (w4 == m) w4 = 0u;
      else if (w5 == m) w5 = 0u;
      thr = m;
    }
    float sd = 0.f;
#pragma unroll
    for (int i = 0; i < 6; ++i) {
      const int idx = i * 64 + lane;
      if (kk[i] >= thr && kk[i] != 0u) sd += down[base + col_b[idx]];
    }
    sd = wave_sum_f(sd);
    if (lane == 0) s_res[1] = sd;
  }
  __syncthreads();

  if (tid == 0 && nv > 0) {
    float SQ = 0.f, SP = 0.f, SYY = 0.f, SYU = 0.f, ASU = 0.f, ASD = 0.f;
#pragma unroll
    for (int w = 0; w < NWAVES; ++w) {
      SQ += red_f[0][w]; SP += red_f[1][w];
      SYY += red_f[2][w]; SYU += red_f[3][w];
      ASU += red_f[4][w]; ASD += red_f[5][w];
    }
    const float SU = s_res[0];
    const float SD = s_res[1];
    // KL closed form: sum q*(logq - logp) = (Seyy - Seyu)/Sq - log(Sq) + log(Sp)
    const float kl = (SYY - SYU) / SQ - __logf(SQ) + __logf(SP);
    const float up_loss = ASU - SU;  // sum softplus(u) - sum_{topk} u
    const float dn_loss = ASD - SD;  // sum softplus(d) - sum_{botk} d
    const float loss = (up_loss + 0.5f * dn_loss + 0.3f * kl) / (float)nv;
    atomicAdd(out, loss * inv_nrows);
  }
}

extern "C" void kernel_launch(void* const* d_in, const int* in_sizes, int n_in,
                              void* d_out, int out_size, void* d_ws, size_t ws_size,
                              hipStream_t stream) {
  const float* up_logits   = (const float*)d_in[0];
  const float* down_logits = (const float*)d_in[1];
  const float* y_true      = (const float*)d_in[2];
  const int*   masks       = (const int*)d_in[3];

  const int nrows = in_sizes[0] / NCOLS;

  hipMemsetAsync(d_out, 0, sizeof(float) * (size_t)out_size, stream);
  row_loss_kernel<<<nrows, BLOCK, 0, stream>>>(up_logits, down_logits, y_true,
                                               masks, (float*)d_out,
                                               1.0f / (float)nrows);
}